// Round 13
// baseline (292.948 us; speedup 1.0000x reference)
//
#include <hip/hip_runtime.h>
#include <hip/hip_bf16.h>

// LGM loss: logits/margin_logits [8192,10000] f32 + scalar likelihood.
// R13: NO-LDS GEMM. Inputs are 9MB total and L2-resident under the XCD
// mapping (guide: "LDS-staging data that L2-fits is pure overhead").
// Direct global->reg MFMA fragment loads: 16 rows x 64B per instr = same
// 64B-granule request count as the staged path, only 2x panel duplication
// (1.29GB L2 reads ~= 37us, overlappable). ZERO barriers, ZERO LDS ->
// waves fully independent: no convoy, stores continuously spread, latency
// hidden by ILP + 16 indep waves/CU. Mapping/epilogue = R6 (best, 200us).

#define ALPHA_ 0.1f
constexpr int BATCH = 8192;
constexpr int NCLS  = 10000;
constexpr int FDIM  = 256;

typedef __attribute__((ext_vector_type(8))) short bf16x8;
typedef __attribute__((ext_vector_type(4))) float f32x4;

__device__ __forceinline__ unsigned short f2bf(float f) {
  unsigned int u = __float_as_uint(f);
  u += 0x7FFF + ((u >> 16) & 1);   // round-to-nearest-even
  return (unsigned short)(u >> 16);
}

// One wave per row: convert f32 row -> bf16 into ws, and compute sum(x*x).
__global__ void prep_kernel(const float* __restrict__ feat,
                            const float* __restrict__ centers,
                            unsigned short* __restrict__ fbf,
                            unsigned short* __restrict__ cbf,
                            float* __restrict__ fsq,
                            float* __restrict__ csq) {
  int gw = (int)((blockIdx.x * blockDim.x + threadIdx.x) >> 6);
  int lane = threadIdx.x & 63;
  if (gw >= BATCH + NCLS) return;
  const float* src; unsigned short* dst; float* sq;
  if (gw < BATCH) {
    src = feat + (size_t)gw * FDIM; dst = fbf + (size_t)gw * FDIM; sq = fsq + gw;
  } else {
    int r = gw - BATCH;
    src = centers + (size_t)r * FDIM; dst = cbf + (size_t)r * FDIM; sq = csq + r;
  }
  float4 v = reinterpret_cast<const float4*>(src)[lane];   // 64 lanes x 16B = 256 f32
  ushort4 b;
  b.x = f2bf(v.x); b.y = f2bf(v.y); b.z = f2bf(v.z); b.w = f2bf(v.w);
  reinterpret_cast<ushort4*>(dst)[lane] = b;
  float s = v.x*v.x + v.y*v.y + v.z*v.z + v.w*v.w;
  #pragma unroll
  for (int off = 32; off >= 1; off >>= 1) s += __shfl_xor(s, off, 64);
  if (lane == 0) *sq = s;
}

// 128x128 tile, 4 waves (2x2), each wave 64x64 via 4x4 frags of 16x16x32.
// No LDS: fragments loaded straight from L2-resident fbf/cbf.
#define BM 128
#define BN 128
constexpr int NTN = 79;                  // N tiles
constexpr int NWG = (BATCH / BM) * NTN;  // 5056 == 8 * 632

__global__ __launch_bounds__(256, 4)
void gemm_kernel(const unsigned short* __restrict__ fbf,
                 const unsigned short* __restrict__ cbf,
                 const float* __restrict__ fsq,
                 const float* __restrict__ csq,
                 const int* __restrict__ label,
                 float* __restrict__ out_logits,
                 float* __restrict__ out_margin,
                 float* __restrict__ lik_row) {
  // XCD-bijective split, nt-fastest within each XCD chunk (A-panel L2 reuse,
  // page-coherent band writes).
  int bid = blockIdx.x;
  int wg = (bid & 7) * (NWG >> 3) + (bid >> 3);
  int mt = wg / NTN;
  int nt = wg - mt * NTN;
  const int c0 = nt * BN;

  const int tid  = threadIdx.x;
  const int lane = tid & 63;
  const int wid  = tid >> 6;            // 0..3
  const int wr   = (wid >> 1) * 64;     // 2 waves in M
  const int wc   = (wid & 1) * 64;      // 2 waves in N
  const int mloc  = wr + (lane & 15);
  const int nbase = wc + ((lane >> 4) << 2);

  // Per-lane fragment row pointers (16B chunk (lane>>4)*8 folded in; kk adds
  // a 64B immediate offset).
  const unsigned short* arow[4];
  const unsigned short* brow[4];
  #pragma unroll
  for (int i = 0; i < 4; i++)
    arow[i] = fbf + (size_t)(mt * BM + wr + i * 16 + (lane & 15)) * FDIM + ((lane >> 4) << 3);
  #pragma unroll
  for (int j = 0; j < 4; j++) {
    int r = c0 + wc + j * 16 + (lane & 15);
    r = (r < NCLS) ? r : (NCLS - 1);    // clamp; results guarded at store
    brow[j] = cbf + (size_t)r * FDIM + ((lane >> 4) << 3);
  }

  f32x4 acc[4][4];
  #pragma unroll
  for (int i = 0; i < 4; i++)
    #pragma unroll
    for (int j = 0; j < 4; j++) acc[i][j] = (f32x4){0.f, 0.f, 0.f, 0.f};

  // K fully unrolled: 8 chunks of K=32; per chunk 8 frag loads + 16 MFMA.
  #pragma unroll
  for (int kk = 0; kk < FDIM / 32; ++kk) {
    bf16x8 a[4], b[4];
    #pragma unroll
    for (int i = 0; i < 4; i++)
      a[i] = *reinterpret_cast<const bf16x8*>(arow[i] + kk * 32);
    #pragma unroll
    for (int j = 0; j < 4; j++)
      b[j] = *reinterpret_cast<const bf16x8*>(brow[j] + kk * 32);
    // Swapped operands: per lane, reg r = 4 consecutive N columns at one M row.
    #pragma unroll
    for (int i = 0; i < 4; i++)
      #pragma unroll
      for (int j = 0; j < 4; j++)
        acc[i][j] = __builtin_amdgcn_mfma_f32_16x16x32_bf16(b[j], a[i], acc[i][j], 0, 0, 0);
  }

  // Epilogue: logits = acc - 0.5*(fsq+csq); margin; lik fold.
  #pragma unroll
  for (int i = 0; i < 4; i++) {
    int m = mt * BM + mloc + i * 16;
    float fs = fsq[m];
    int lb = label[m];
    size_t rowoff = (size_t)m * NCLS;
    #pragma unroll
    for (int j = 0; j < 4; j++) {
      int n0 = c0 + nbase + j * 16;
      if (n0 >= NCLS) continue;   // NCLS%4==0 and n0%4==0 -> float4 all-or-nothing
      float4 cs = *reinterpret_cast<const float4*>(&csq[n0]);
      f32x4 v = acc[i][j];
      f32x4 lg;
      lg[0] = v[0] - 0.5f * (fs + cs.x);
      lg[1] = v[1] - 0.5f * (fs + cs.y);
      lg[2] = v[2] - 0.5f * (fs + cs.z);
      lg[3] = v[3] - 0.5f * (fs + cs.w);
      *reinterpret_cast<f32x4*>(&out_logits[rowoff + n0]) = lg;
      f32x4 mg;
      mg[0] = (lb == n0    ) ? lg[0] * (1.0f + ALPHA_) : lg[0];
      mg[1] = (lb == n0 + 1) ? lg[1] * (1.0f + ALPHA_) : lg[1];
      mg[2] = (lb == n0 + 2) ? lg[2] * (1.0f + ALPHA_) : lg[2];
      mg[3] = (lb == n0 + 3) ? lg[3] * (1.0f + ALPHA_) : lg[3];
      *reinterpret_cast<f32x4*>(&out_margin[rowoff + n0]) = mg;
      if (lb >= n0 && lb < n0 + 4) {
        float lv = (lb == n0) ? lg[0] : (lb == n0 + 1) ? lg[1]
                 : (lb == n0 + 2) ? lg[2] : lg[3];
        lik_row[m] = -lv;   // exactly one thread in grid writes each m
      }
    }
  }
}

// likelihood = (1/B) * sum_m lik_row[m]; 1024 threads, deterministic tree.
__global__ void lik_reduce_kernel(const float* __restrict__ lik_row,
                                  float* __restrict__ out) {
  int t = threadIdx.x;  // 1024
  float v = 0.f;
  #pragma unroll
  for (int i = 0; i < BATCH / 1024; i++) v += lik_row[t + i * 1024];
  #pragma unroll
  for (int off = 32; off >= 1; off >>= 1) v += __shfl_xor(v, off, 64);
  __shared__ float red[16];
  if ((t & 63) == 0) red[t >> 6] = v;
  __syncthreads();
  if (t == 0) {
    float s = 0.f;
    #pragma unroll
    for (int i = 0; i < 16; i++) s += red[i];
    out[0] = s * (1.0f / BATCH);
  }
}

extern "C" void kernel_launch(void* const* d_in, const int* in_sizes, int n_in,
                              void* d_out, int out_size, void* d_ws, size_t ws_size,
                              hipStream_t stream) {
  const float* feat    = (const float*)d_in[0];
  const int*   label   = (const int*)d_in[1];
  const float* centers = (const float*)d_in[2];

  float* out        = (float*)d_out;
  float* out_logits = out;
  float* out_margin = out + (size_t)BATCH * NCLS;
  float* out_lik    = out + 2 * (size_t)BATCH * NCLS;

  char* ws = (char*)d_ws;
  unsigned short* fbf = (unsigned short*)ws;                                   // 4 MB
  unsigned short* cbf = (unsigned short*)(ws + (size_t)BATCH * FDIM * 2);      // 5 MB
  float* fsq     = (float*)(ws + (size_t)BATCH * FDIM * 2 + (size_t)NCLS * FDIM * 2);
  float* csq     = fsq + BATCH;
  float* lik_row = csq + NCLS;

  prep_kernel<<<(BATCH + NCLS) / 4, 256, 0, stream>>>(feat, centers, fbf, cbf, fsq, csq);
  gemm_kernel<<<NWG, 256, 0, stream>>>(
      fbf, cbf, fsq, csq, label, out_logits, out_margin, lik_row);
  lik_reduce_kernel<<<1, 1024, 0, stream>>>(lik_row, out_lik);
}

// Round 14
// 197.084 us; speedup vs baseline: 1.4864x; 1.4864x over previous
//
#include <hip/hip_runtime.h>
#include <hip/hip_bf16.h>

// LGM loss: logits/margin_logits [8192,10000] f32 + scalar likelihood.
// R14: PARITY-ALIGNED STORES. Row stride 40000B == 64 mod 128: every odd
// output row's 512B tile segment is 64B-misaligned to 128B L2 lines -> 2
// partial half-lines per odd tile-row per output -> RFO fetch + double
// writeback. Predicted 166MB fetch + 83MB write-amp matches R11's counters
// (198MB FETCH, +121MB WRITE). Fix: each wave computes a 16-col halo frag
// (j=0 at wc-16, +50% MFMA at 9% util = cheap) and stores per row parity:
//   even rows: cols [c0+wc, +32)      (start % 128 == 0)
//   odd rows:  cols [c0+wc-16, +16)   (start = 64+64 == 0 mod 128)
// Exact partition of [0,10000) per parity; guards drop n0<0 / >=NCLS.
// Everything else = R6 (best, 200us): BK=64 dbuf reg-staged, XOR swizzle,
// nt-fastest XCD mapping, lik fold. Bs grows a 16-row halo (LDS 68KB).

#define ALPHA_ 0.1f
constexpr int BATCH = 8192;
constexpr int NCLS  = 10000;
constexpr int FDIM  = 256;

typedef __attribute__((ext_vector_type(8))) short bf16x8;
typedef __attribute__((ext_vector_type(4))) float f32x4;

__device__ __forceinline__ unsigned short f2bf(float f) {
  unsigned int u = __float_as_uint(f);
  u += 0x7FFF + ((u >> 16) & 1);   // round-to-nearest-even
  return (unsigned short)(u >> 16);
}

// One wave per row: convert f32 row -> bf16 into ws, and compute sum(x*x).
__global__ void prep_kernel(const float* __restrict__ feat,
                            const float* __restrict__ centers,
                            unsigned short* __restrict__ fbf,
                            unsigned short* __restrict__ cbf,
                            float* __restrict__ fsq,
                            float* __restrict__ csq) {
  int gw = (int)((blockIdx.x * blockDim.x + threadIdx.x) >> 6);
  int lane = threadIdx.x & 63;
  if (gw >= BATCH + NCLS) return;
  const float* src; unsigned short* dst; float* sq;
  if (gw < BATCH) {
    src = feat + (size_t)gw * FDIM; dst = fbf + (size_t)gw * FDIM; sq = fsq + gw;
  } else {
    int r = gw - BATCH;
    src = centers + (size_t)r * FDIM; dst = cbf + (size_t)r * FDIM; sq = csq + r;
  }
  float4 v = reinterpret_cast<const float4*>(src)[lane];   // 64 lanes x 16B = 256 f32
  ushort4 b;
  b.x = f2bf(v.x); b.y = f2bf(v.y); b.z = f2bf(v.z); b.w = f2bf(v.w);
  reinterpret_cast<ushort4*>(dst)[lane] = b;
  float s = v.x*v.x + v.y*v.y + v.z*v.z + v.w*v.w;
  #pragma unroll
  for (int off = 32; off >= 1; off >>= 1) s += __shfl_xor(s, off, 64);
  if (lane == 0) *sq = s;
}

// 128x128 tile (+16-col B halo), BK=64, 8 waves (2Mx4N), wave = 64x32 (+16 halo).
#define BM 128
#define BN 128
#define BK 64
#define BROWS 144   // 16-row halo + 128

__global__ __launch_bounds__(512, 4)
void gemm_kernel(const unsigned short* __restrict__ fbf,
                 const unsigned short* __restrict__ cbf,
                 const float* __restrict__ fsq,
                 const float* __restrict__ csq,
                 const int* __restrict__ label,
                 float* __restrict__ out_logits,
                 float* __restrict__ out_margin,
                 float* __restrict__ lik_row) {
  // Double-buffered, XOR-swizzled (slot = chunk ^ (row&7), 16B chunks).
  __shared__ unsigned short As[2][BM * BK];      // 16 KB each
  __shared__ unsigned short Bs[2][BROWS * BK];   // 18 KB each -> 68 KB total

  const int NTN = (NCLS + BN - 1) / BN;  // 79
  const int NWG = (BATCH / BM) * NTN;    // 5056 == 8 * 632

  // XCD-bijective split, nt-fastest within each XCD chunk.
  int bid = blockIdx.x;
  int wg = (bid & 7) * (NWG >> 3) + (bid >> 3);
  int mt = wg / NTN;
  int nt = wg - mt * NTN;

  const int tid  = threadIdx.x;
  const int lane = tid & 63;
  const int wid  = tid >> 6;            // 0..7
  const int wr   = (wid >> 2) * 64;     // 2 waves in M
  const int wc   = (wid & 3) * 32;      // 4 waves in N
  const int sr   = tid >> 3;            // staging row 0..63
  const int sc   = tid & 7;             // staging 16B chunk 0..7
  const int mloc  = wr + (lane & 15);

  const size_t a_base = (size_t)(mt * BM) * FDIM;
  const int c0 = nt * BN;

  f32x4 acc[4][3];   // 3 N-frags: j=0 is the 16-col halo at wc-16
  #pragma unroll
  for (int i = 0; i < 4; i++)
    #pragma unroll
    for (int j = 0; j < 3; j++) acc[i][j] = (f32x4){0.f, 0.f, 0.f, 0.f};

  bf16x8 va[2], vb[2], vbh;

  // Bs row r <-> class c0 - 16 + r, r in [0,144).
  #define LOADT(k0_) do {                                                      \
    _Pragma("unroll")                                                          \
    for (int j = 0; j < 2; ++j) {                                              \
      int r = j * 64 + sr;                                                     \
      va[j] = *reinterpret_cast<const bf16x8*>(fbf + a_base + (size_t)r * FDIM + (k0_) + sc * 8); \
      int cc = c0 + r; cc = (cc < NCLS) ? cc : (NCLS - 1);                     \
      vb[j] = *reinterpret_cast<const bf16x8*>(cbf + (size_t)cc * FDIM + (k0_) + sc * 8); \
    }                                                                          \
    if (tid < 128) {                                                           \
      int ch_ = c0 - 16 + (tid >> 3); ch_ = (ch_ >= 0) ? ch_ : 0;              \
      vbh = *reinterpret_cast<const bf16x8*>(cbf + (size_t)ch_ * FDIM + (k0_) + sc * 8); \
    }                                                                          \
  } while (0)

  #define STORET(b_) do {                                                      \
    _Pragma("unroll")                                                          \
    for (int j = 0; j < 2; ++j) {                                              \
      int r = j * 64 + sr;                                                     \
      int offa = r * BK + ((sc ^ (r & 7)) * 8);                                \
      *reinterpret_cast<bf16x8*>(&As[b_][offa]) = va[j];                       \
      int rb = r + 16;                                                         \
      int offb = rb * BK + ((sc ^ (rb & 7)) * 8);                              \
      *reinterpret_cast<bf16x8*>(&Bs[b_][offb]) = vb[j];                       \
    }                                                                          \
    if (tid < 128) {                                                           \
      int rh = tid >> 3;                                                       \
      int offh = rh * BK + ((sc ^ (rh & 7)) * 8);                              \
      *reinterpret_cast<bf16x8*>(&Bs[b_][offh]) = vbh;                         \
    }                                                                          \
  } while (0)

  LOADT(0);
  STORET(0);

  #pragma unroll
  for (int kc = 0; kc < FDIM / BK; ++kc) {
    const int cur = kc & 1;
    if (kc < FDIM / BK - 1) LOADT((kc + 1) * BK);
    __syncthreads();                          // buf[cur] writes visible
    #pragma unroll
    for (int kk = 0; kk < BK / 32; ++kk) {
      const int ch = kk * 4 + (lane >> 4);    // 16B chunk within row
      bf16x8 a[4], b[3];
      #pragma unroll
      for (int i = 0; i < 4; i++) {
        int row = wr + i * 16 + (lane & 15);
        a[i] = *reinterpret_cast<const bf16x8*>(&As[cur][row * BK + ((ch ^ (row & 7)) * 8)]);
      }
      #pragma unroll
      for (int j = 0; j < 3; j++) {
        int row = wc + j * 16 + (lane & 15);  // class c0 + wc + (j-1)*16 + (lane&15)
        b[j] = *reinterpret_cast<const bf16x8*>(&Bs[cur][row * BK + ((ch ^ (row & 7)) * 8)]);
      }
      // Swapped operands: per lane, reg r = 4 consecutive N columns at one M row.
      #pragma unroll
      for (int i = 0; i < 4; i++)
        #pragma unroll
        for (int j = 0; j < 3; j++)
          acc[i][j] = __builtin_amdgcn_mfma_f32_16x16x32_bf16(b[j], a[i], acc[i][j], 0, 0, 0);
    }
    if (kc < FDIM / BK - 1) STORET(cur ^ 1);  // fill other buffer
  }

  // Epilogue with parity-aligned windows.
  // Lane's rows have parity p = lane&1 (mt*128, wr, i*16 all even).
  // Store frag j at n0 = c0 + wc + (j-1)*16 + (lane>>4)*4:
  //   even rows (p=0): j=1,2  -> cols [c0+wc, +32), 128B-aligned rows
  //   odd  rows (p=1): j=0,1  -> cols [c0+wc-16, +16), start also 0 mod 128
  const int p = lane & 1;
  #pragma unroll
  for (int i = 0; i < 4; i++) {
    int m = mt * BM + mloc + i * 16;
    float fs = fsq[m];
    int lb = label[m];
    size_t rowoff = (size_t)m * NCLS;
    #pragma unroll
    for (int j = 0; j < 3; j++) {
      if (p ? (j >= 2) : (j == 0)) continue;
      int n0 = c0 + wc + (j - 1) * 16 + ((lane >> 4) << 2);
      if (n0 < 0 || n0 >= NCLS) continue;  // n0%4==0, NCLS%4==0 -> all-or-nothing
      float4 cs = *reinterpret_cast<const float4*>(&csq[n0]);
      f32x4 v = acc[i][j];
      f32x4 lg;
      lg[0] = v[0] - 0.5f * (fs + cs.x);
      lg[1] = v[1] - 0.5f * (fs + cs.y);
      lg[2] = v[2] - 0.5f * (fs + cs.z);
      lg[3] = v[3] - 0.5f * (fs + cs.w);
      *reinterpret_cast<f32x4*>(&out_logits[rowoff + n0]) = lg;
      f32x4 mg;
      mg[0] = (lb == n0    ) ? lg[0] * (1.0f + ALPHA_) : lg[0];
      mg[1] = (lb == n0 + 1) ? lg[1] * (1.0f + ALPHA_) : lg[1];
      mg[2] = (lb == n0 + 2) ? lg[2] * (1.0f + ALPHA_) : lg[2];
      mg[3] = (lb == n0 + 3) ? lg[3] * (1.0f + ALPHA_) : lg[3];
      *reinterpret_cast<f32x4*>(&out_margin[rowoff + n0]) = mg;
      if (lb >= n0 && lb < n0 + 4) {
        float lv = (lb == n0) ? lg[0] : (lb == n0 + 1) ? lg[1]
                 : (lb == n0 + 2) ? lg[2] : lg[3];
        lik_row[m] = -lv;   // exactly-once partition per parity -> one writer
      }
    }
  }
  #undef LOADT
  #undef STORET
}

// likelihood = (1/B) * sum_m lik_row[m]; 1024 threads, deterministic tree.
__global__ void lik_reduce_kernel(const float* __restrict__ lik_row,
                                  float* __restrict__ out) {
  int t = threadIdx.x;  // 1024
  float v = 0.f;
  #pragma unroll
  for (int i = 0; i < BATCH / 1024; i++) v += lik_row[t + i * 1024];
  #pragma unroll
  for (int off = 32; off >= 1; off >>= 1) v += __shfl_xor(v, off, 64);
  __shared__ float red[16];
  if ((t & 63) == 0) red[t >> 6] = v;
  __syncthreads();
  if (t == 0) {
    float s = 0.f;
    #pragma unroll
    for (int i = 0; i < 16; i++) s += red[i];
    out[0] = s * (1.0f / BATCH);
  }
}

extern "C" void kernel_launch(void* const* d_in, const int* in_sizes, int n_in,
                              void* d_out, int out_size, void* d_ws, size_t ws_size,
                              hipStream_t stream) {
  const float* feat    = (const float*)d_in[0];
  const int*   label   = (const int*)d_in[1];
  const float* centers = (const float*)d_in[2];

  float* out        = (float*)d_out;
  float* out_logits = out;
  float* out_margin = out + (size_t)BATCH * NCLS;
  float* out_lik    = out + 2 * (size_t)BATCH * NCLS;

  char* ws = (char*)d_ws;
  unsigned short* fbf = (unsigned short*)ws;                                   // 4 MB
  unsigned short* cbf = (unsigned short*)(ws + (size_t)BATCH * FDIM * 2);      // 5 MB
  float* fsq     = (float*)(ws + (size_t)BATCH * FDIM * 2 + (size_t)NCLS * FDIM * 2);
  float* csq     = fsq + BATCH;
  float* lik_row = csq + NCLS;

  prep_kernel<<<(BATCH + NCLS) / 4, 256, 0, stream>>>(feat, centers, fbf, cbf, fsq, csq);
  gemm_kernel<<<(BATCH / BM) * ((NCLS + BN - 1) / BN), 512, 0, stream>>>(
      fbf, cbf, fsq, csq, label, out_logits, out_margin, lik_row);
  lik_reduce_kernel<<<1, 1024, 0, stream>>>(lik_row, out_lik);
}